// Round 2
// baseline (2700.754 us; speedup 1.0000x reference)
//
#include <hip/hip_runtime.h>

// OptionNet fused kernels for MI355X (gfx950), fp32 vector-FMA path.
//
//   K0 (detect): determine dones layout (bool bytes vs int32) -> ws flag.
//   K1 (MODE 0, meta):  hm=relu(obs@Wm1+bm1); heads Wm_pi(8)+Wm_v(1) fused.
//   K2 (MODE 1, term):  ht=relu(obs@Wt1); head Wt2(8) fused; bucket rows.
//   K3 (MODE 2, sub):   per-option gathered rows; experts run only on their
//                       own rows (1/8 of the reference's expert FLOPs).

constexpr int Bn = 32768;
constexpr int Dk = 512;
constexpr int Hn = 1024;

constexpr int ROWS = 64;    // rows per block
constexpr int HC   = 128;   // hidden-column chunk per head-fusion step
constexpr int KT   = 16;    // K tile staged in LDS
constexpr int NT   = 256;   // threads per block
constexpr int TILES_PER_OPT = Bn / ROWS; // 512

// Detect dones layout. Bool-byte layout: bytes at offsets %4!=0 carry data
// (p=0.05 over 32768 rows -> ~1600 nonzero, certain hit). Int32 layout with
// values in {0,1}: upper 3 bytes of every word are 0. Scans 32KB (safe for
// both: bool buffer is exactly 32KB, int32 buffer is 128KB).
__global__ void k_detect(const unsigned int* __restrict__ w, int* __restrict__ flag)
{
    unsigned int acc = 0;
    for (int i = threadIdx.x; i < 8192; i += blockDim.x) acc |= w[i];
    if (acc & 0xFFFFFF00u) atomicOr(flag, 1);
}

template<int CA, int CB, bool HASBIAS, int MODE>
__global__ __launch_bounds__(NT, 2)
void k_fused(const float* __restrict__ obs,
             const float* __restrict__ WhB,
             const float* __restrict__ biasB,
             const float* __restrict__ WAB,
             const float* __restrict__ WBB,
             float* __restrict__ out,
             int* __restrict__ counts,
             unsigned short* __restrict__ buckets,
             const void* __restrict__ dones,
             const int* __restrict__ dflag,
             const int* __restrict__ execopt)
{
    constexpr int CT  = CA + CB;          // total head cols (<=17)
    constexpr int CPT = (CT + 3) / 4;     // head cols per thread (4 threads/row)

    __shared__ float s_obsT[KT][ROWS + 4];   // transposed obs tile
    __shared__ float s_W[KT][HC + 4];        // hidden-weight tile
    __shared__ float s_h[ROWS][HC + 4];      // activated hidden chunk
    __shared__ float s_WhT[17][HC + 4];      // head weights (transposed)
    __shared__ float s_logits[ROWS][20];     // final head outputs
    __shared__ float s_bias[HC];
    __shared__ int   s_idx[ROWS];

    const int tid = threadIdx.x;
    int nrows = ROWS;
    int o = 0;

    const float* Wh   = WhB;
    const float* bias = biasB;
    const float* WA   = WAB;
    const float* WB   = WBB;

    if constexpr (MODE == 2) {
        o = blockIdx.x >> 9;             // 512 tiles per option
        const int t = blockIdx.x & 511;
        const int n = counts[o];
        const int start = t * ROWS;
        if (start >= n) return;          // uniform early exit (before any sync)
        nrows = min(ROWS, n - start);
        if (tid < ROWS)
            s_idx[tid] = (int)buckets[o * Bn + start + min(tid, nrows - 1)];
        Wh   = WhB   + (size_t)o * Dk * Hn;
        bias = biasB + (size_t)o * Hn;
        WA   = WAB   + (size_t)o * Hn * 16;
        WB   = WBB   + (size_t)o * Hn;
    } else {
        if (tid < ROWS) s_idx[tid] = blockIdx.x * ROWS + tid;
    }
    __syncthreads();

    // main-GEMM micro-tile mapping: 16x16 thread grid, 4 rows x 8 cols each
    const int tc = tid & 15;   // col group
    const int tr = tid >> 4;   // row group
    // head-phase mapping: 4 threads per row
    const int hr = tid >> 2;   // row 0..63
    const int hq = tid & 3;    // col quarter

    // staging mapping for obs tile
    const int ld_row = tid >> 2;         // 0..63
    const int ld_kk  = (tid & 3) * 4;    // 0,4,8,12

    float head_acc[CPT];
#pragma unroll
    for (int i = 0; i < CPT; ++i) head_acc[i] = 0.f;

    for (int hc = 0; hc < Hn; hc += HC) {
        // ---- load head weights (+bias) for this chunk ----
        for (int e = tid; e < CT * HC; e += NT) {
            const int c = e >> 7;          // e / HC
            const int j = e & (HC - 1);    // e % HC
            float v;
            if (c < CA) v = WA[(size_t)(hc + j) * CA + c];
            else        v = WB[(size_t)(hc + j) * CB + (c - CA)];
            s_WhT[c][j] = v;
        }
        if constexpr (HASBIAS) {
            if (tid < HC) s_bias[tid] = bias[hc + tid];
        }

        float acc[4][8];
#pragma unroll
        for (int i = 0; i < 4; ++i)
#pragma unroll
            for (int j = 0; j < 8; ++j) acc[i][j] = 0.f;

        // ---- K loop: S[64][128] = obs_tile @ W[:, hc:hc+128] ----
        for (int kt = 0; kt < Dk; kt += KT) {
            __syncthreads();   // protect prior reads of s_obsT/s_W (and s_WhT store)
            {
                const int gr = s_idx[ld_row];
                const float4 v = *reinterpret_cast<const float4*>(
                    obs + (size_t)gr * Dk + kt + ld_kk);
                s_obsT[ld_kk + 0][ld_row] = v.x;
                s_obsT[ld_kk + 1][ld_row] = v.y;
                s_obsT[ld_kk + 2][ld_row] = v.z;
                s_obsT[ld_kk + 3][ld_row] = v.w;
            }
#pragma unroll
            for (int p = 0; p < 2; ++p) {
                const int L  = tid + p * NT;
                const int k  = L >> 5;
                const int cg = (L & 31) * 4;
                const float4 v = *reinterpret_cast<const float4*>(
                    Wh + (size_t)(kt + k) * Hn + hc + cg);
                *reinterpret_cast<float4*>(&s_W[k][cg]) = v;
            }
            __syncthreads();
#pragma unroll
            for (int k = 0; k < KT; ++k) {
                const float4 av = *reinterpret_cast<const float4*>(&s_obsT[k][tr * 4]);
                const float4 b0 = *reinterpret_cast<const float4*>(&s_W[k][tc * 4]);
                const float4 b1 = *reinterpret_cast<const float4*>(&s_W[k][64 + tc * 4]);
                float a_[4], b_[8];
                a_[0] = av.x; a_[1] = av.y; a_[2] = av.z; a_[3] = av.w;
                b_[0] = b0.x; b_[1] = b0.y; b_[2] = b0.z; b_[3] = b0.w;
                b_[4] = b1.x; b_[5] = b1.y; b_[6] = b1.z; b_[7] = b1.w;
#pragma unroll
                for (int i = 0; i < 4; ++i)
#pragma unroll
                    for (int j = 0; j < 8; ++j)
                        acc[i][j] = fmaf(a_[i], b_[j], acc[i][j]);
            }
        }

        // ---- bias + relu, stage h chunk ----
#pragma unroll
        for (int i = 0; i < 4; ++i) {
            const int r = tr * 4 + i;
            float4 v0, v1;
            v0.x = acc[i][0]; v0.y = acc[i][1]; v0.z = acc[i][2]; v0.w = acc[i][3];
            v1.x = acc[i][4]; v1.y = acc[i][5]; v1.z = acc[i][6]; v1.w = acc[i][7];
            if constexpr (HASBIAS) {
                v0.x += s_bias[tc * 4 + 0]; v0.y += s_bias[tc * 4 + 1];
                v0.z += s_bias[tc * 4 + 2]; v0.w += s_bias[tc * 4 + 3];
                v1.x += s_bias[64 + tc * 4 + 0]; v1.y += s_bias[64 + tc * 4 + 1];
                v1.z += s_bias[64 + tc * 4 + 2]; v1.w += s_bias[64 + tc * 4 + 3];
            }
            v0.x = fmaxf(v0.x, 0.f); v0.y = fmaxf(v0.y, 0.f);
            v0.z = fmaxf(v0.z, 0.f); v0.w = fmaxf(v0.w, 0.f);
            v1.x = fmaxf(v1.x, 0.f); v1.y = fmaxf(v1.y, 0.f);
            v1.z = fmaxf(v1.z, 0.f); v1.w = fmaxf(v1.w, 0.f);
            *reinterpret_cast<float4*>(&s_h[r][tc * 4])      = v0;
            *reinterpret_cast<float4*>(&s_h[r][64 + tc * 4]) = v1;
        }
        __syncthreads();

        // ---- head accumulation: logits[r][c] += h[r][:] . WhT[c][:] ----
        {
            const float* hrow = s_h[hr];
#pragma unroll
            for (int i = 0; i < CPT; ++i) {
                const int c = hq * CPT + i;
                if (c < CT) {
                    const float* wrow = s_WhT[c];
                    float a = head_acc[i];
#pragma unroll
                    for (int j = 0; j < HC; j += 4) {
                        const float4 hv = *reinterpret_cast<const float4*>(&hrow[j]);
                        const float4 wv = *reinterpret_cast<const float4*>(&wrow[j]);
                        a = fmaf(hv.x, wv.x, a);
                        a = fmaf(hv.y, wv.y, a);
                        a = fmaf(hv.z, wv.z, a);
                        a = fmaf(hv.w, wv.w, a);
                    }
                    head_acc[i] = a;
                }
            }
        }
        __syncthreads();   // protect s_WhT/s_bias/s_h for next chunk
    }

    // ---- publish logits to LDS ----
#pragma unroll
    for (int i = 0; i < CPT; ++i) {
        const int c = hq * CPT + i;
        if (c < CT) s_logits[hr][c] = head_acc[i];
    }
    __syncthreads();

    // ---- epilogues ----
    if constexpr (MODE == 0) {          // meta
        if (tid < ROWS) {
            const int g = s_idx[tid];
            float m = s_logits[tid][0]; int am = 0;
#pragma unroll
            for (int j = 1; j < 8; ++j) {
                const float x = s_logits[tid][j];
                if (x > m) { m = x; am = j; }
            }
            float s = 0.f;
#pragma unroll
            for (int j = 0; j < 8; ++j) s += expf(s_logits[tid][j] - m);
            const float lp = -logf(s);   // logp at argmax (shifted[am]==0)
            out[3 * Bn + g] = (float)am;
            out[4 * Bn + g] = s_logits[tid][8];
            out[5 * Bn + g] = lp;
        }
    } else if constexpr (MODE == 1) {   // termination + bucketing
        if (tid < ROWS) {
            const int g  = s_idx[tid];
            const int eo = execopt[g];
            const float logit = s_logits[tid][eo];
            const float p = 1.f / (1.f + expf(-logit));
            out[6 * Bn + g] = p;
            bool dn;
            if (*dflag) dn = ((const unsigned char*)dones)[g] != 0;  // bool bytes
            else        dn = ((const int*)dones)[g] != 0;            // int32
            const bool term = dn || (p > 0.5f);
            const int  ma   = (int)out[3 * Bn + g];   // meta action from MODE 0
            const int  no   = term ? ma : eo;
            const int  pos  = atomicAdd(&counts[no], 1);
            buckets[no * Bn + pos] = (unsigned short)g;
        }
    } else {                            // sub-policy
        if (tid < nrows) {
            const int g = s_idx[tid];
            float m = s_logits[tid][0]; int am = 0;
#pragma unroll
            for (int j = 1; j < 16; ++j) {
                const float x = s_logits[tid][j];
                if (x > m) { m = x; am = j; }
            }
            float s = 0.f;
#pragma unroll
            for (int j = 0; j < 16; ++j) s += expf(s_logits[tid][j] - m);
            const float lp = -logf(s);
            out[0 * Bn + g] = (float)am;
            out[1 * Bn + g] = s_logits[tid][16];
            out[2 * Bn + g] = lp;
        }
    }
}

extern "C" void kernel_launch(void* const* d_in, const int* in_sizes, int n_in,
                              void* d_out, int out_size, void* d_ws, size_t ws_size,
                              hipStream_t stream)
{
    const float* obs    = (const float*)d_in[0];
    const void*  dones  = d_in[1];               // bool bytes OR int32 (detected)
    const int*   execopt= (const int*)d_in[2];
    const float* Wm1    = (const float*)d_in[3];
    const float* bm1    = (const float*)d_in[4];
    const float* Wm_pi  = (const float*)d_in[5];
    const float* Wm_v   = (const float*)d_in[6];
    const float* Wt1    = (const float*)d_in[7];
    const float* Wt2    = (const float*)d_in[8];
    const float* W1     = (const float*)d_in[9];
    const float* b1     = (const float*)d_in[10];
    const float* Wpi    = (const float*)d_in[11];
    const float* Wv     = (const float*)d_in[12];
    float* out = (float*)d_out;

    // ws layout: [0..31] counts (8 ints), [32..35] dones-layout flag,
    //            [64..] buckets u16 (8 * 32768 * 2 = 512 KiB)
    int* counts = (int*)d_ws;
    int* dflag  = (int*)((char*)d_ws + 32);
    unsigned short* buckets = (unsigned short*)((char*)d_ws + 64);

    hipMemsetAsync(d_ws, 0, 64, stream);   // zero counters + flag

    dim3 blk(NT);
    k_detect<<<1, blk, 0, stream>>>((const unsigned int*)dones, dflag);
    // meta: hm = relu(obs@Wm1+bm1); heads [Wm_pi | Wm_v]
    k_fused<8, 1, true, 0><<<Bn / ROWS, blk, 0, stream>>>(
        obs, Wm1, bm1, Wm_pi, Wm_v, out, counts, buckets, dones, dflag, execopt);
    // term: ht = relu(obs@Wt1); head Wt2; bucket rows by new_option
    k_fused<8, 0, false, 1><<<Bn / ROWS, blk, 0, stream>>>(
        obs, Wt1, nullptr, Wt2, nullptr, out, counts, buckets, dones, dflag, execopt);
    // sub-policy: gathered rows per option
    k_fused<16, 1, true, 2><<<8 * TILES_PER_OPT, blk, 0, stream>>>(
        obs, W1, b1, Wpi, Wv, out, counts, buckets, dones, dflag, execopt);
}

// Round 3
// 736.759 us; speedup vs baseline: 3.6657x; 3.6657x over previous
//
#include <hip/hip_runtime.h>

// OptionNet on MI355X — split-bf16 MFMA path (fp32-accurate via hi/lo planes).
//
//   prep:  k_split_hid  — 10 hidden W matrices -> 2 bf16 planes, [n][k] layout (ws)
//          k_split_head — 10 head sets -> 2 bf16 planes, [32 cols][k] zero-padded (ws)
//   k_gemm<MODE>: 128x128 tile, 4 waves, K-step 32, 4-term MFMA emulation of fp32.
//          Per-chunk head logits via MFMA from LDS-staged h, atomicAdd to ws logits.
//   k_epi_meta / k_epi_term / k_epi_sub: row-wise epilogues (argmax, log-softmax,
//          sigmoid+bucketing by new_option).
//   Sub-policy runs only on its bucketed rows (1/8 of reference expert FLOPs).
//   Fallback: if ws_size < WS_NEED, launch the Round-2 fp32 kernel (passing).

constexpr int Bn = 32768;
constexpr int Dk = 512;
constexpr int Hn = 1024;

typedef __attribute__((ext_vector_type(8))) short short8v;
typedef __attribute__((ext_vector_type(4))) float f32x4;

__device__ __forceinline__ unsigned short f2bf(float x) {
    unsigned u = __float_as_uint(x);
    u += 0x7FFFu + ((u >> 16) & 1u);
    return (unsigned short)(u >> 16);
}
__device__ __forceinline__ float bf2f(unsigned short h) {
    return __uint_as_float(((unsigned)h) << 16);
}

// ---------------- workspace layout ----------------
constexpr size_t WS_COUNTS  = 0;          // 8 ints
constexpr size_t WS_DFLAG   = 32;         // 1 int
constexpr size_t WS_BUCKETS = 64;         // u16 [8][32768] = 524288 B
constexpr size_t WS_LOGITS  = 1u << 20;   // 3 x [32768][20] f32 = 7864320 B
constexpr size_t LOG_SZ     = (size_t)Bn * 20 * 4;        // 2621440
constexpr size_t WS_HID     = 16u << 20;  // [10][2][1024][512] bf16 = 20971520 B
constexpr size_t WS_HEAD    = 40u << 20;  // [10][2][32][1024] bf16 = 1310720 B
constexpr size_t WS_NEED    = WS_HEAD + (size_t)10 * 2 * 32 * 1024 * 2;

// ---------------- dones layout detect ----------------
__global__ void k_detect(const unsigned int* __restrict__ w, int* __restrict__ flag)
{
    unsigned int acc = 0;
    for (int i = threadIdx.x; i < 8192; i += blockDim.x) acc |= w[i];
    if (acc & 0xFFFFFF00u) atomicOr(flag, 1);
}

// ---------------- weight split preps ----------------
__global__ __launch_bounds__(256)
void k_split_hid(const float* __restrict__ Wm1, const float* __restrict__ Wt1,
                 const float* __restrict__ W1, unsigned short* __restrict__ dst)
{
    const int bid = blockIdx.x;
    const int m  = bid >> 7;          // 0..9
    const int t  = bid & 127;
    const int k0 = (t >> 4) << 6;     // 8 k-tiles of 64
    const int n0 = (t & 15) << 6;     // 16 n-tiles of 64
    const float* src = (m == 0) ? Wm1 : (m == 1) ? Wt1 : (W1 + (size_t)(m - 2) * Dk * Hn);

    __shared__ unsigned short sT[2][64][72];   // [pl][n][k], stride 72 (16B-aligned rows)
    const int tid = threadIdx.x;
    const int kk = tid >> 2;            // 0..63
    const int nc = (tid & 3) << 4;      // 0,16,32,48
    const float* p = src + (size_t)(k0 + kk) * Hn + n0 + nc;
#pragma unroll
    for (int i = 0; i < 4; ++i) {
        const float4 v = *(const float4*)(p + i * 4);
        float xs[4] = {v.x, v.y, v.z, v.w};
#pragma unroll
        for (int e = 0; e < 4; ++e) {
            const unsigned short h = f2bf(xs[e]);
            const unsigned short l = f2bf(xs[e] - bf2f(h));
            sT[0][nc + i * 4 + e][kk] = h;
            sT[1][nc + i * 4 + e][kk] = l;
        }
    }
    __syncthreads();
    if (tid < 128) {
        const int pl = tid >> 6, n = tid & 63;
        unsigned short* dp = dst + ((size_t)(m * 2 + pl) * 1024 + n0 + n) * 512 + k0;
        const unsigned short* sp = &sT[pl][n][0];
#pragma unroll
        for (int i = 0; i < 8; ++i)
            *(short8v*)(dp + i * 8) = *(const short8v*)(sp + i * 8);
    }
}

__global__ __launch_bounds__(256)
void k_split_head(const float* __restrict__ Wm_pi, const float* __restrict__ Wm_v,
                  const float* __restrict__ Wt2, const float* __restrict__ Wpi,
                  const float* __restrict__ Wv, unsigned short* __restrict__ dst)
{
    const int set = blockIdx.x >> 5, c = blockIdx.x & 31;
    const int tid = threadIdx.x;
    unsigned short* d0 = dst + ((size_t)(set * 2 + 0) * 32 + c) * 1024;
    unsigned short* d1 = dst + ((size_t)(set * 2 + 1) * 32 + c) * 1024;
#pragma unroll
    for (int i = 0; i < 4; ++i) {
        const int k = tid + i * 256;
        float x = 0.f;
        if (set == 0)      { if (c < 8) x = Wm_pi[k * 8 + c]; else if (c == 8) x = Wm_v[k]; }
        else if (set == 1) { if (c < 8) x = Wt2[k * 8 + c]; }
        else { const int o = set - 2;
               if (c < 16) x = Wpi[((size_t)o * 1024 + k) * 16 + c];
               else if (c == 16) x = Wv[o * 1024 + k]; }
        const unsigned short h = f2bf(x);
        d0[k] = h;
        d1[k] = f2bf(x - bf2f(h));
    }
}

// ---------------- main fused GEMM ----------------
// LDS s_raw map (bytes):
//   K-loop:  A planes [buf][pl][128 rows][64B]  at 0      .. 32767
//            B planes [buf][pl][128 cols][64B]  at 32768  .. 65535
//   post-K:  s_h  f32 [64][132]                 at 0      .. 33791
//            s_hB bf16 [pl][32 cols][136]       at 33792  .. 51199
template<int MODE, int CT>
__global__ __launch_bounds__(256, 2)
void k_gemm(const float* __restrict__ obs,
            const unsigned short* __restrict__ hidPl,
            const unsigned short* __restrict__ headPl,
            const float* __restrict__ bm1,
            const float* __restrict__ b1,
            float* __restrict__ L,
            const int* __restrict__ counts,
            const unsigned short* __restrict__ buckets)
{
    __shared__ __align__(16) unsigned char s_raw[65536];
    __shared__ float s_bias[128];
    __shared__ int   s_idx[128];

    const int tid = threadIdx.x;
    const int bid = blockIdx.x;

    int mat, set, ch, nrows = 128;
    const float* bias = nullptr;

    if constexpr (MODE == 2) {
        const int o = bid >> 11, rem = bid & 2047;
        const int x = rem & 7;  ch = (rem >> 3) & 7;
        const int rt = x + ((rem >> 6) << 3);
        const int n = counts[o], start = rt << 7;
        if (start >= n) return;                  // uniform early exit, pre-sync
        nrows = min(128, n - start);
        if (tid < 128) s_idx[tid] = (int)buckets[(o << 15) + start + min(tid, nrows - 1)];
        mat = 2 + o; set = 2 + o; bias = b1 + (size_t)o * Hn;
    } else {
        const int x = bid & 7;  ch = (bid >> 3) & 7;
        const int rt = x + ((bid >> 6) << 3);
        if (tid < 128) s_idx[tid] = (rt << 7) + tid;
        mat = MODE; set = MODE; bias = (MODE == 0) ? bm1 : nullptr;
    }
    const int hc = ch << 7;
    if (tid < 128) s_bias[tid] = (MODE == 1) ? 0.f : bias[hc + tid];
    __syncthreads();

    const int l = tid & 63, w = tid >> 6;
    const int r15 = l & 15, q = l >> 4;
    const int R0 = (w >> 1) * 64, C0 = (w & 1) * 64;

    // staging roles
    const int arow = tid >> 1, ahalf = tid & 1;          // A: 2 threads/row, 16 floats each
    const int bpl = tid >> 7, bn = tid & 127;            // B: 1 thread per (plane,col)
    const size_t arowg = (size_t)s_idx[arow] * Dk;
    const unsigned short* bptr = hidPl + ((size_t)(mat * 2 + bpl) * 1024 + (hc + bn)) * 512;

    f32x4 acc[4][4];
#pragma unroll
    for (int i = 0; i < 4; ++i)
#pragma unroll
        for (int j = 0; j < 4; ++j) acc[i][j] = (f32x4){0.f, 0.f, 0.f, 0.f};

    float4  av[4];
    short8v bv[4];

    auto stage_load = [&](int kt) {
        const float* p = obs + arowg + kt * 32 + ahalf * 16;
        av[0] = *(const float4*)(p);      av[1] = *(const float4*)(p + 4);
        av[2] = *(const float4*)(p + 8);  av[3] = *(const float4*)(p + 12);
        const unsigned short* bp = bptr + kt * 32;
#pragma unroll
        for (int j = 0; j < 4; ++j) bv[j] = *(const short8v*)(bp + j * 8);
    };

    auto stage_write = [&](int buf) {
        float xs[16] = {av[0].x, av[0].y, av[0].z, av[0].w,  av[1].x, av[1].y, av[1].z, av[1].w,
                        av[2].x, av[2].y, av[2].z, av[2].w,  av[3].x, av[3].y, av[3].z, av[3].w};
        short8v H0, H1, Lo0, Lo1;
#pragma unroll
        for (int e = 0; e < 8; ++e) {
            unsigned short h = f2bf(xs[e]);
            H0[e] = (short)h;  Lo0[e] = (short)f2bf(xs[e] - bf2f(h));
            h = f2bf(xs[8 + e]);
            H1[e] = (short)h;  Lo1[e] = (short)f2bf(xs[8 + e] - bf2f(h));
        }
        const int sw  = (arow >> 1) & 3;
        const int ra  = arow * 64;
        unsigned char* a0 = s_raw + (buf * 2 + 0) * 8192 + ra;
        unsigned char* a1 = s_raw + (buf * 2 + 1) * 8192 + ra;
        const int q0 = ((2 * ahalf) ^ sw) << 4, q1 = ((2 * ahalf + 1) ^ sw) << 4;
        *(short8v*)(a0 + q0) = H0;  *(short8v*)(a0 + q1) = H1;
        *(short8v*)(a1 + q0) = Lo0; *(short8v*)(a1 + q1) = Lo1;

        const int swb = (bn >> 1) & 3;
        unsigned char* bb = s_raw + 32768 + (buf * 2 + bpl) * 8192 + bn * 64;
#pragma unroll
        for (int j = 0; j < 4; ++j)
            *(short8v*)(bb + ((j ^ swb) << 4)) = bv[j];
    };

    auto mfma_step = [&](int buf) {
        short8v a[2][4], b[2][4];
#pragma unroll
        for (int rf = 0; rf < 4; ++rf) {
            const int row = R0 + rf * 16 + r15;
            const int off = row * 64 + ((q ^ ((row >> 1) & 3)) << 4);
            a[0][rf] = *(const short8v*)(s_raw + (buf * 2 + 0) * 8192 + off);
            a[1][rf] = *(const short8v*)(s_raw + (buf * 2 + 1) * 8192 + off);
        }
#pragma unroll
        for (int cf = 0; cf < 4; ++cf) {
            const int n = C0 + cf * 16 + r15;
            const int off = n * 64 + ((q ^ ((n >> 1) & 3)) << 4);
            b[0][cf] = *(const short8v*)(s_raw + 32768 + (buf * 2 + 0) * 8192 + off);
            b[1][cf] = *(const short8v*)(s_raw + 32768 + (buf * 2 + 1) * 8192 + off);
        }
#pragma unroll
        for (int t = 0; t < 4; ++t) {                 // (lo,lo),(lo,hi),(hi,lo),(hi,hi)
            const int pa = 1 - (t >> 1), pb = 1 - (t & 1);
#pragma unroll
            for (int rf = 0; rf < 4; ++rf)
#pragma unroll
                for (int cf = 0; cf < 4; ++cf)
                    acc[rf][cf] = __builtin_amdgcn_mfma_f32_16x16x32_bf16(
                        a[pa][rf], b[pb][cf], acc[rf][cf], 0, 0, 0);
        }
    };

    stage_load(0);
    stage_write(0);
    __syncthreads();
#pragma unroll 1
    for (int kt = 0; kt < 16; ++kt) {
        const int cb = kt & 1;
        if (kt < 15) stage_load(kt + 1);     // loads in flight under MFMA
        mfma_step(cb);
        if (kt < 15) stage_write(cb ^ 1);
        __syncthreads();
    }

    // ---- stage head-weight planes into s_hB ----
    {
        const int pl = tid >> 7, idx = tid & 127, c = idx >> 2, kq = idx & 3;
        const unsigned short* hp = headPl + ((size_t)(set * 2 + pl) * 32 + c) * 1024 + hc + kq * 32;
        short8v h0 = *(const short8v*)(hp);      short8v h1 = *(const short8v*)(hp + 8);
        short8v h2 = *(const short8v*)(hp + 16); short8v h3 = *(const short8v*)(hp + 24);
        unsigned char* d = s_raw + 33792 + pl * 8704 + c * 272 + kq * 64;
        ((short8v*)d)[0] = h0; ((short8v*)d)[1] = h1; ((short8v*)d)[2] = h2; ((short8v*)d)[3] = h3;
    }

    float* sh = (float*)s_raw;   // [64][132]
#pragma unroll 1
    for (int half = 0; half < 2; ++half) {
        if ((w >> 1) == half) {           // owning waves write bias+relu(h) rows
#pragma unroll
            for (int rf = 0; rf < 4; ++rf)
#pragma unroll
                for (int cf = 0; cf < 4; ++cf) {
                    const int c = C0 + cf * 16 + r15;
                    const float bs = s_bias[c];
#pragma unroll
                    for (int reg = 0; reg < 4; ++reg) {
                        const int r = rf * 16 + q * 4 + reg;
                        sh[r * 132 + c] = fmaxf(acc[rf][cf][reg] + bs, 0.f);
                    }
                }
        }
        __syncthreads();

        f32x4 hacc[2];
        hacc[0] = (f32x4){0.f, 0.f, 0.f, 0.f};
        hacc[1] = (f32x4){0.f, 0.f, 0.f, 0.f};
#pragma unroll
        for (int ks = 0; ks < 4; ++ks) {
            const float* shp = sh + (w * 16 + r15) * 132 + ks * 32 + q * 8;
            const float4 f0 = *(const float4*)(shp);
            const float4 f1 = *(const float4*)(shp + 4);
            const float xs[8] = {f0.x, f0.y, f0.z, f0.w, f1.x, f1.y, f1.z, f1.w};
            short8v ah, al;
#pragma unroll
            for (int j = 0; j < 8; ++j) {
                const unsigned short h = f2bf(xs[j]);
                ah[j] = (short)h;
                al[j] = (short)f2bf(xs[j] - bf2f(h));
            }
#pragma unroll
            for (int cf = 0; cf < 2; ++cf) {
                const unsigned char* hb = s_raw + 33792 + (cf * 16 + r15) * 272 + ks * 64 + q * 16;
                const short8v b0 = *(const short8v*)(hb);          // hi plane
                const short8v b1 = *(const short8v*)(hb + 8704);   // lo plane
                hacc[cf] = __builtin_amdgcn_mfma_f32_16x16x32_bf16(al, b1, hacc[cf], 0, 0, 0);
                hacc[cf] = __builtin_amdgcn_mfma_f32_16x16x32_bf16(al, b0, hacc[cf], 0, 0, 0);
                hacc[cf] = __builtin_amdgcn_mfma_f32_16x16x32_bf16(ah, b1, hacc[cf], 0, 0, 0);
                hacc[cf] = __builtin_amdgcn_mfma_f32_16x16x32_bf16(ah, b0, hacc[cf], 0, 0, 0);
            }
        }
#pragma unroll
        for (int cf = 0; cf < 2; ++cf) {
            const int c = cf * 16 + r15;
            if (c < CT) {
#pragma unroll
                for (int reg = 0; reg < 4; ++reg) {
                    const int rl = half * 64 + w * 16 + q * 4 + reg;
                    if (rl < nrows)
                        atomicAdd(&L[(size_t)s_idx[rl] * 20 + c], hacc[cf][reg]);
                }
            }
        }
        __syncthreads();
    }
}

// ---------------- epilogues ----------------
__global__ __launch_bounds__(256)
void k_epi_meta(const float* __restrict__ L, float* __restrict__ out)
{
    const int g = blockIdx.x * 256 + threadIdx.x;
    const float* lr = L + (size_t)g * 20;
    float m = lr[0]; int am = 0;
#pragma unroll
    for (int j = 1; j < 8; ++j) { const float x = lr[j]; if (x > m) { m = x; am = j; } }
    float s = 0.f;
#pragma unroll
    for (int j = 0; j < 8; ++j) s += expf(lr[j] - m);
    out[3 * Bn + g] = (float)am;
    out[4 * Bn + g] = lr[8];
    out[5 * Bn + g] = -logf(s);
}

__global__ __launch_bounds__(256)
void k_epi_term(const float* __restrict__ L, float* __restrict__ out,
                const int* __restrict__ execopt, const void* __restrict__ dones,
                const int* __restrict__ dflag, int* __restrict__ counts,
                unsigned short* __restrict__ buckets)
{
    const int g = blockIdx.x * 256 + threadIdx.x;
    const int eo = execopt[g];
    const float logit = L[(size_t)g * 20 + eo];
    const float p = 1.f / (1.f + expf(-logit));
    out[6 * Bn + g] = p;
    bool dn;
    if (*dflag) dn = ((const unsigned char*)dones)[g] != 0;
    else        dn = ((const int*)dones)[g] != 0;
    const int ma = (int)out[3 * Bn + g];
    const int no = (dn || (p > 0.5f)) ? ma : eo;
    const int pos = atomicAdd(&counts[no], 1);
    buckets[(no << 15) + pos] = (unsigned short)g;
}

__global__ __launch_bounds__(256)
void k_epi_sub(const float* __restrict__ L, float* __restrict__ out)
{
    const int g = blockIdx.x * 256 + threadIdx.x;
    const float* lr = L + (size_t)g * 20;
    float m = lr[0]; int am = 0;
#pragma unroll
    for (int j = 1; j < 16; ++j) { const float x = lr[j]; if (x > m) { m = x; am = j; } }
    float s = 0.f;
#pragma unroll
    for (int j = 0; j < 16; ++j) s += expf(lr[j] - m);
    out[0 * Bn + g] = (float)am;
    out[1 * Bn + g] = lr[16];
    out[2 * Bn + g] = -logf(s);
}

// ================= Round-2 fp32 fallback (passing) =================
constexpr int FB_ROWS = 64;
constexpr int FB_HC   = 128;
constexpr int FB_KT   = 16;
constexpr int FB_NT   = 256;

template<int CA, int CB, bool HASBIAS, int MODE>
__global__ __launch_bounds__(FB_NT, 2)
void k_fused_fb(const float* __restrict__ obs, const float* __restrict__ WhB,
                const float* __restrict__ biasB, const float* __restrict__ WAB,
                const float* __restrict__ WBB, float* __restrict__ out,
                int* __restrict__ counts, unsigned short* __restrict__ buckets,
                const void* __restrict__ dones, const int* __restrict__ dflag,
                const int* __restrict__ execopt)
{
    constexpr int CT  = CA + CB;
    constexpr int CPT = (CT + 3) / 4;

    __shared__ float s_obsT[FB_KT][FB_ROWS + 4];
    __shared__ float s_W[FB_KT][FB_HC + 4];
    __shared__ float s_h[FB_ROWS][FB_HC + 4];
    __shared__ float s_WhT[17][FB_HC + 4];
    __shared__ float s_logits[FB_ROWS][20];
    __shared__ float s_bias[FB_HC];
    __shared__ int   s_idx[FB_ROWS];

    const int tid = threadIdx.x;
    int nrows = FB_ROWS;
    const float* Wh = WhB; const float* bias = biasB;
    const float* WA = WAB; const float* WB = WBB;

    if constexpr (MODE == 2) {
        const int o = blockIdx.x >> 9;
        const int t = blockIdx.x & 511;
        const int n = counts[o];
        const int start = t * FB_ROWS;
        if (start >= n) return;
        nrows = min(FB_ROWS, n - start);
        if (tid < FB_ROWS) s_idx[tid] = (int)buckets[o * Bn + start + min(tid, nrows - 1)];
        Wh = WhB + (size_t)o * Dk * Hn; bias = biasB + (size_t)o * Hn;
        WA = WAB + (size_t)o * Hn * 16; WB = WBB + (size_t)o * Hn;
    } else {
        if (tid < FB_ROWS) s_idx[tid] = blockIdx.x * FB_ROWS + tid;
    }
    __syncthreads();

    const int tc = tid & 15, tr = tid >> 4;
    const int hr = tid >> 2, hq = tid & 3;
    const int ld_row = tid >> 2, ld_kk = (tid & 3) * 4;

    float head_acc[CPT];
#pragma unroll
    for (int i = 0; i < CPT; ++i) head_acc[i] = 0.f;

    for (int hcc = 0; hcc < Hn; hcc += FB_HC) {
        for (int e = tid; e < CT * FB_HC; e += FB_NT) {
            const int c = e >> 7, j = e & (FB_HC - 1);
            float v;
            if (c < CA) v = WA[(size_t)(hcc + j) * CA + c];
            else        v = WB[(size_t)(hcc + j) * CB + (c - CA)];
            s_WhT[c][j] = v;
        }
        if constexpr (HASBIAS) { if (tid < FB_HC) s_bias[tid] = bias[hcc + tid]; }

        float acc[4][8];
#pragma unroll
        for (int i = 0; i < 4; ++i)
#pragma unroll
            for (int j = 0; j < 8; ++j) acc[i][j] = 0.f;

        for (int kt = 0; kt < Dk; kt += FB_KT) {
            __syncthreads();
            {
                const int gr = s_idx[ld_row];
                const float4 v = *reinterpret_cast<const float4*>(obs + (size_t)gr * Dk + kt + ld_kk);
                s_obsT[ld_kk + 0][ld_row] = v.x; s_obsT[ld_kk + 1][ld_row] = v.y;
                s_obsT[ld_kk + 2][ld_row] = v.z; s_obsT[ld_kk + 3][ld_row] = v.w;
            }
#pragma unroll
            for (int p = 0; p < 2; ++p) {
                const int Li = tid + p * FB_NT;
                const int k = Li >> 5, cg = (Li & 31) * 4;
                *reinterpret_cast<float4*>(&s_W[k][cg]) =
                    *reinterpret_cast<const float4*>(Wh + (size_t)(kt + k) * Hn + hcc + cg);
            }
            __syncthreads();
#pragma unroll
            for (int k = 0; k < FB_KT; ++k) {
                const float4 avv = *reinterpret_cast<const float4*>(&s_obsT[k][tr * 4]);
                const float4 b0 = *reinterpret_cast<const float4*>(&s_W[k][tc * 4]);
                const float4 b1 = *reinterpret_cast<const float4*>(&s_W[k][64 + tc * 4]);
                float a_[4] = {avv.x, avv.y, avv.z, avv.w};
                float b_[8] = {b0.x, b0.y, b0.z, b0.w, b1.x, b1.y, b1.z, b1.w};
#pragma unroll
                for (int i = 0; i < 4; ++i)
#pragma unroll
                    for (int j = 0; j < 8; ++j) acc[i][j] = fmaf(a_[i], b_[j], acc[i][j]);
            }
        }

#pragma unroll
        for (int i = 0; i < 4; ++i) {
            const int r = tr * 4 + i;
            float4 v0, v1;
            v0.x = acc[i][0]; v0.y = acc[i][1]; v0.z = acc[i][2]; v0.w = acc[i][3];
            v1.x = acc[i][4]; v1.y = acc[i][5]; v1.z = acc[i][6]; v1.w = acc[i][7];
            if constexpr (HASBIAS) {
                v0.x += s_bias[tc * 4 + 0]; v0.y += s_bias[tc * 4 + 1];
                v0.z += s_bias[tc * 4 + 2]; v0.w += s_bias[tc * 4 + 3];
                v1.x += s_bias[64 + tc * 4 + 0]; v1.y += s_bias[64 + tc * 4 + 1];
                v1.z += s_bias[64 + tc * 4 + 2]; v1.w += s_bias[64 + tc * 4 + 3];
            }
            v0.x = fmaxf(v0.x, 0.f); v0.y = fmaxf(v0.y, 0.f);
            v0.z = fmaxf(v0.z, 0.f); v0.w = fmaxf(v0.w, 0.f);
            v1.x = fmaxf(v1.x, 0.f); v1.y = fmaxf(v1.y, 0.f);
            v1.z = fmaxf(v1.z, 0.f); v1.w = fmaxf(v1.w, 0.f);
            *reinterpret_cast<float4*>(&s_h[r][tc * 4]) = v0;
            *reinterpret_cast<float4*>(&s_h[r][64 + tc * 4]) = v1;
        }
        __syncthreads();
        {
            const float* hrow = s_h[hr];
#pragma unroll
            for (int i = 0; i < CPT; ++i) {
                const int c = hq * CPT + i;
                if (c < CT) {
                    const float* wrow = s_WhT[c];
                    float a = head_acc[i];
#pragma unroll
                    for (int j = 0; j < FB_HC; j += 4) {
                        const float4 hv = *reinterpret_cast<const float4*>(&hrow[j]);
                        const float4 wv = *reinterpret_cast<const float4*>(&wrow[j]);
                        a = fmaf(hv.x, wv.x, a); a = fmaf(hv.y, wv.y, a);
                        a = fmaf(hv.z, wv.z, a); a = fmaf(hv.w, wv.w, a);
                    }
                    head_acc[i] = a;
                }
            }
        }
        __syncthreads();
    }

#pragma unroll
    for (int i = 0; i < CPT; ++i) {
        const int c = hq * CPT + i;
        if (c < CT) s_logits[hr][c] = head_acc[i];
    }
    __syncthreads();

    if constexpr (MODE == 0) {
        if (tid < FB_ROWS) {
            const int g = s_idx[tid];
            float m = s_logits[tid][0]; int am = 0;
#pragma unroll
            for (int j = 1; j < 8; ++j) { const float x = s_logits[tid][j]; if (x > m) { m = x; am = j; } }
            float s = 0.f;
#pragma unroll
            for (int j = 0; j < 8; ++j) s += expf(s_logits[tid][j] - m);
            out[3 * Bn + g] = (float)am;
            out[4 * Bn + g] = s_logits[tid][8];
            out[5 * Bn + g] = -logf(s);
        }
    } else if constexpr (MODE == 1) {
        if (tid < FB_ROWS) {
            const int g = s_idx[tid];
            const int eo = execopt[g];
            const float p = 1.f / (1.f + expf(-s_logits[tid][eo]));
            out[6 * Bn + g] = p;
            bool dn;
            if (*dflag) dn = ((const unsigned char*)dones)[g] != 0;
            else        dn = ((const int*)dones)[g] != 0;
            const int no = (dn || (p > 0.5f)) ? (int)out[3 * Bn + g] : eo;
            const int pos = atomicAdd(&counts[no], 1);
            buckets[no * Bn + pos] = (unsigned short)g;
        }
    } else {
        if (tid < nrows) {
            const int g = s_idx[tid];
            float m = s_logits[tid][0]; int am = 0;
#pragma unroll
            for (int j = 1; j < 16; ++j) { const float x = s_logits[tid][j]; if (x > m) { m = x; am = j; } }
            float s = 0.f;
#pragma unroll
            for (int j = 0; j < 16; ++j) s += expf(s_logits[tid][j] - m);
            out[0 * Bn + g] = (float)am;
            out[1 * Bn + g] = s_logits[tid][16];
            out[2 * Bn + g] = -logf(s);
        }
    }
}

// ---------------- launcher ----------------
extern "C" void kernel_launch(void* const* d_in, const int* in_sizes, int n_in,
                              void* d_out, int out_size, void* d_ws, size_t ws_size,
                              hipStream_t stream)
{
    const float* obs     = (const float*)d_in[0];
    const void*  dones   = d_in[1];
    const int*   execopt = (const int*)d_in[2];
    const float* Wm1   = (const float*)d_in[3];
    const float* bm1   = (const float*)d_in[4];
    const float* Wm_pi = (const float*)d_in[5];
    const float* Wm_v  = (const float*)d_in[6];
    const float* Wt1   = (const float*)d_in[7];
    const float* Wt2   = (const float*)d_in[8];
    const float* W1    = (const float*)d_in[9];
    const float* b1    = (const float*)d_in[10];
    const float* Wpi   = (const float*)d_in[11];
    const float* Wv    = (const float*)d_in[12];
    float* out = (float*)d_out;

    unsigned char* ws = (unsigned char*)d_ws;
    int* counts = (int*)(ws + WS_COUNTS);
    int* dflag  = (int*)(ws + WS_DFLAG);
    unsigned short* buckets = (unsigned short*)(ws + WS_BUCKETS);

    hipMemsetAsync(d_ws, 0, 64, stream);
    k_detect<<<1, 256, 0, stream>>>((const unsigned int*)dones, dflag);

    if (ws_size >= WS_NEED) {
        float* metaL = (float*)(ws + WS_LOGITS);
        float* termL = (float*)(ws + WS_LOGITS + LOG_SZ);
        float* subL  = (float*)(ws + WS_LOGITS + 2 * LOG_SZ);
        unsigned short* hidPl  = (unsigned short*)(ws + WS_HID);
        unsigned short* headPl = (unsigned short*)(ws + WS_HEAD);

        hipMemsetAsync(ws + WS_LOGITS, 0, 3 * LOG_SZ, stream);
        k_split_hid<<<1280, 256, 0, stream>>>(Wm1, Wt1, W1, hidPl);
        k_split_head<<<320, 256, 0, stream>>>(Wm_pi, Wm_v, Wt2, Wpi, Wv, headPl);

        k_gemm<0, 9><<<2048, 256, 0, stream>>>(obs, hidPl, headPl, bm1, b1, metaL, counts, buckets);
        k_epi_meta<<<128, 256, 0, stream>>>(metaL, out);
        k_gemm<1, 8><<<2048, 256, 0, stream>>>(obs, hidPl, headPl, bm1, b1, termL, counts, buckets);
        k_epi_term<<<128, 256, 0, stream>>>(termL, out, execopt, dones, dflag, counts, buckets);
        k_gemm<2, 17><<<16384, 256, 0, stream>>>(obs, hidPl, headPl, bm1, b1, subL, counts, buckets);
        k_epi_sub<<<128, 256, 0, stream>>>(subL, out);
    } else {
        // Round-2 fp32 fallback
        k_fused_fb<8, 1, true, 0><<<Bn / FB_ROWS, FB_NT, 0, stream>>>(
            obs, Wm1, bm1, Wm_pi, Wm_v, out, counts, buckets, dones, dflag, execopt);
        k_fused_fb<8, 0, false, 1><<<Bn / FB_ROWS, FB_NT, 0, stream>>>(
            obs, Wt1, nullptr, Wt2, nullptr, out, counts, buckets, dones, dflag, execopt);
        k_fused_fb<16, 1, true, 2><<<8 * (Bn / FB_ROWS), FB_NT, 0, stream>>>(
            obs, W1, b1, Wpi, Wv, out, counts, buckets, dones, dflag, execopt);
    }
}

// Round 6
// 668.225 us; speedup vs baseline: 4.0417x; 1.1026x over previous
//
#include <hip/hip_runtime.h>

// OptionNet on MI355X — split-bf16 MFMA path, async-staged (global_load_lds).
//
//   k_split_obs:  obs f32 -> 2 bf16 planes [2][32768][512] (ws)
//   k_split_hid:  10 hidden W -> 2 bf16 planes, [n][k] layout (ws)
//   k_split_head: 10 head sets -> 2 bf16 planes, [32 cols][k] padded (ws)
//   k_gemm<3>:    fused meta+term GEMMs (128x128 tile, 4 waves, K-step 32,
//                 3-term MFMA split: hi*hi + hi*lo + lo*hi).
//   k_epi_mt:     meta argmax/softmax/value + termination sigmoid + bucketing.
//   k_gemm<2>:    per-option sub-policy on bucketed rows only (1/8 FLOPs).
//   k_epi_sub:    sub argmax/softmax/value.
//   A/B staged via global_load_lds w=16 with pre-swizzled per-lane source
//   addresses (LDS dest linear); ds_read applies the same XOR.
//   Fallbacks: mid-ws (A reg-staged) and fp32 (Round-2 kernel).

constexpr int Bn = 32768;
constexpr int Dk = 512;
constexpr int Hn = 1024;

typedef __attribute__((ext_vector_type(8))) short short8v;
typedef __attribute__((ext_vector_type(4))) float f32x4;

__device__ __forceinline__ unsigned short f2bf(float x) {
    unsigned u = __float_as_uint(x);
    u += 0x7FFFu + ((u >> 16) & 1u);
    return (unsigned short)(u >> 16);
}
__device__ __forceinline__ float bf2f(unsigned short h) {
    return __uint_as_float(((unsigned)h) << 16);
}

__device__ __forceinline__ void gload16(const void* g, void* l) {
    __builtin_amdgcn_global_load_lds(
        (const __attribute__((address_space(1))) unsigned int*)g,
        (__attribute__((address_space(3))) unsigned int*)l, 16, 0, 0);
}

// ---------------- workspace layout ----------------
constexpr size_t WS_COUNTS  = 0;           // 8 ints
constexpr size_t WS_DFLAG   = 32;          // 1 int
constexpr size_t WS_BUCKETS = 64;          // u16 [8][32768]
constexpr size_t WS_LOGITS  = 1u << 20;    // 3 x [32768][20] f32
constexpr size_t LOG_SZ     = (size_t)Bn * 20 * 4;
constexpr size_t WS_HID     = 16u << 20;   // [10][2][1024][512] bf16
constexpr size_t WS_HEAD    = 40u << 20;   // [10][2][32][1024] bf16
constexpr size_t WS_OBS     = 42u << 20;   // [2][32768][512] bf16
constexpr size_t MID_NEED   = WS_HEAD + (size_t)10 * 2 * 32 * 1024 * 2;
constexpr size_t FULL_NEED  = WS_OBS + (size_t)2 * Bn * Dk * 2;

// ---------------- dones layout detect ----------------
__global__ void k_detect(const unsigned int* __restrict__ w, int* __restrict__ flag)
{
    unsigned int acc = 0;
    for (int i = threadIdx.x; i < 8192; i += blockDim.x) acc |= w[i];
    if (acc & 0xFFFFFF00u) atomicOr(flag, 1);
}

// ---------------- prep kernels ----------------
__global__ __launch_bounds__(256)
void k_split_obs(const float* __restrict__ obs, unsigned short* __restrict__ dst)
{
    const size_t i = ((size_t)blockIdx.x * 256 + threadIdx.x) * 8;
    const float4 v0 = *(const float4*)(obs + i);
    const float4 v1 = *(const float4*)(obs + i + 4);
    const float xs[8] = {v0.x, v0.y, v0.z, v0.w, v1.x, v1.y, v1.z, v1.w};
    short8v hi, lo;
#pragma unroll
    for (int e = 0; e < 8; ++e) {
        const unsigned short h = f2bf(xs[e]);
        hi[e] = (short)h;
        lo[e] = (short)f2bf(xs[e] - bf2f(h));
    }
    *(short8v*)(dst + i) = hi;
    *(short8v*)(dst + (size_t)Bn * Dk + i) = lo;
}

__global__ __launch_bounds__(256)
void k_split_hid(const float* __restrict__ Wm1, const float* __restrict__ Wt1,
                 const float* __restrict__ W1, unsigned short* __restrict__ dst)
{
    const int bid = blockIdx.x;
    const int m  = bid >> 7;
    const int t  = bid & 127;
    const int k0 = (t >> 4) << 6;
    const int n0 = (t & 15) << 6;
    const float* src = (m == 0) ? Wm1 : (m == 1) ? Wt1 : (W1 + (size_t)(m - 2) * Dk * Hn);

    __shared__ unsigned short sT[2][64][72];
    const int tid = threadIdx.x;
    const int kk = tid >> 2;
    const int nc = (tid & 3) << 4;
    const float* p = src + (size_t)(k0 + kk) * Hn + n0 + nc;
#pragma unroll
    for (int i = 0; i < 4; ++i) {
        const float4 v = *(const float4*)(p + i * 4);
        float xs[4] = {v.x, v.y, v.z, v.w};
#pragma unroll
        for (int e = 0; e < 4; ++e) {
            const unsigned short h = f2bf(xs[e]);
            const unsigned short l = f2bf(xs[e] - bf2f(h));
            sT[0][nc + i * 4 + e][kk] = h;
            sT[1][nc + i * 4 + e][kk] = l;
        }
    }
    __syncthreads();
    if (tid < 128) {
        const int pl = tid >> 6, n = tid & 63;
        unsigned short* dp = dst + ((size_t)(m * 2 + pl) * 1024 + n0 + n) * 512 + k0;
        const unsigned short* sp = &sT[pl][n][0];
#pragma unroll
        for (int i = 0; i < 8; ++i)
            *(short8v*)(dp + i * 8) = *(const short8v*)(sp + i * 8);
    }
}

__global__ __launch_bounds__(256)
void k_split_head(const float* __restrict__ Wm_pi, const float* __restrict__ Wm_v,
                  const float* __restrict__ Wt2, const float* __restrict__ Wpi,
                  const float* __restrict__ Wv, unsigned short* __restrict__ dst)
{
    const int set = blockIdx.x >> 5, c = blockIdx.x & 31;
    const int tid = threadIdx.x;
    unsigned short* d0 = dst + ((size_t)(set * 2 + 0) * 32 + c) * 1024;
    unsigned short* d1 = dst + ((size_t)(set * 2 + 1) * 32 + c) * 1024;
#pragma unroll
    for (int i = 0; i < 4; ++i) {
        const int k = tid + i * 256;
        float x = 0.f;
        if (set == 0)      { if (c < 8) x = Wm_pi[k * 8 + c]; else if (c == 8) x = Wm_v[k]; }
        else if (set == 1) { if (c < 8) x = Wt2[k * 8 + c]; }
        else { const int o = set - 2;
               if (c < 16) x = Wpi[((size_t)o * 1024 + k) * 16 + c];
               else if (c == 16) x = Wv[o * 1024 + k]; }
        const unsigned short h = f2bf(x);
        d0[k] = h;
        d1[k] = f2bf(x - bf2f(h));
    }
}

// ---------------- main fused GEMM ----------------
// LDS s_raw map (bytes):
//   K-loop:  A planes [buf][pl][128 rows][64B]  at 0      .. 32767
//            B planes [buf][pl][128 cols][64B]  at 32768  .. 65535
//   post-K:  s_h  f32 [64][132]                 at 0      .. 33791
//            s_hB bf16 [pl][32 cols][272B]      at 33792  .. 51199
// MODE 3: fused meta+term (bid = x(3) | ch(3) | mat(1) | rtHigh)
// MODE 2: sub-policy on bucketed rows (bid = o(3 hi) | rt/ch interleave)
template<int MODE, bool APL>
__global__ __launch_bounds__(256, 2)
void k_gemm(const float* __restrict__ obs,
            const unsigned short* __restrict__ obsPl,
            const unsigned short* __restrict__ hidPl,
            const unsigned short* __restrict__ headPl,
            const float* __restrict__ bm1,
            const float* __restrict__ b1,
            float* __restrict__ metaL, float* __restrict__ termL,
            float* __restrict__ subL,
            const int* __restrict__ counts,
            const unsigned short* __restrict__ buckets)
{
    __shared__ __align__(16) unsigned char s_raw[65536];
    __shared__ float s_bias[128];
    __shared__ int   s_idx[128];

    const int tid = threadIdx.x;
    const int bid = blockIdx.x;

    int mat, set, ch, CT, nrows = 128;
    float* L;
    const float* bias = nullptr;

    if constexpr (MODE == 2) {
        const int o = bid >> 11, rem = bid & 2047;
        const int x = rem & 7;  ch = (rem >> 3) & 7;
        const int rt = x + ((rem >> 6) << 3);
        const int n = counts[o], start = rt << 7;
        if (start >= n) return;                  // uniform early exit, pre-sync
        nrows = min(128, n - start);
        if (tid < 128) s_idx[tid] = (int)buckets[(o << 15) + start + min(tid, nrows - 1)];
        mat = 2 + o; set = 2 + o; bias = b1 + (size_t)o * Hn; L = subL; CT = 17;
    } else {                                     // MODE 3: fused meta + term
        const int x = bid & 7;  ch = (bid >> 3) & 7;  mat = (bid >> 6) & 1;
        const int rt = x + ((bid >> 7) << 3);
        if (tid < 128) s_idx[tid] = (rt << 7) + tid;
        set = mat; CT = mat ? 8 : 9;
        L = mat ? termL : metaL;
        bias = mat ? nullptr : bm1;
    }
    const int hc = ch << 7;
    if (tid < 128) s_bias[tid] = (bias == nullptr) ? 0.f : bias[hc + tid];
    __syncthreads();

    const int l = tid & 63, w = tid >> 6;
    const int r15 = l & 15, qq = l >> 4;
    const int R0 = (w >> 1) * 64, C0 = (w & 1) * 64;

    f32x4 acc[4][4];
#pragma unroll
    for (int i = 0; i < 4; ++i)
#pragma unroll
        for (int j = 0; j < 4; ++j) acc[i][j] = (f32x4){0.f, 0.f, 0.f, 0.f};

    // ---- staging bases (per-lane global addresses, pre-XOR'd quads) ----
    const int spl = w >> 1;                 // plane this wave stages
    const int sg0 = (w & 1) * 4;            // first 16-row/col group
    const unsigned char* bB[4];
#pragma unroll
    for (int j = 0; j < 4; ++j) {
        const int cl = (sg0 + j) * 16 + (l >> 2);
        const int qd = ((l & 3) ^ ((cl >> 1) & 3)) << 4;
        bB[j] = (const unsigned char*)hidPl
              + ((size_t)(mat * 2 + spl) * 1024 + hc + cl) * 1024 + qd;
    }
    const unsigned char* aB[4];
    if constexpr (APL) {
#pragma unroll
        for (int j = 0; j < 4; ++j) {
            const int rl = (sg0 + j) * 16 + (l >> 2);
            const int qd = ((l & 3) ^ ((rl >> 1) & 3)) << 4;
            aB[j] = (const unsigned char*)obsPl
                  + ((size_t)spl * Bn + (size_t)s_idx[rl]) * 1024 + qd;
        }
    }

    auto stage = [&](int buf, int kt) {
#pragma unroll
        for (int j = 0; j < 4; ++j) {
            if constexpr (APL)
                gload16(aB[j] + kt * 64,
                        s_raw + (buf * 2 + spl) * 8192 + (sg0 + j) * 1024);
            gload16(bB[j] + kt * 64,
                    s_raw + 32768 + (buf * 2 + spl) * 8192 + (sg0 + j) * 1024);
        }
    };

    // ---- A reg-staging fallback (mid-ws path) ----
    const int arow = tid >> 1, ahalf = tid & 1;
    size_t arowg = 0;
    if constexpr (!APL) arowg = (size_t)s_idx[arow] * Dk;
    float4 av[4];
    auto loadA = [&](int kt) {
        const float* p = obs + arowg + kt * 32 + ahalf * 16;
        av[0] = *(const float4*)(p);      av[1] = *(const float4*)(p + 4);
        av[2] = *(const float4*)(p + 8);  av[3] = *(const float4*)(p + 12);
    };
    auto writeA = [&](int buf) {
        float xs[16] = {av[0].x, av[0].y, av[0].z, av[0].w,  av[1].x, av[1].y, av[1].z, av[1].w,
                        av[2].x, av[2].y, av[2].z, av[2].w,  av[3].x, av[3].y, av[3].z, av[3].w};
        short8v H0, H1, Lo0, Lo1;
#pragma unroll
        for (int e = 0; e < 8; ++e) {
            unsigned short h = f2bf(xs[e]);
            H0[e] = (short)h;  Lo0[e] = (short)f2bf(xs[e] - bf2f(h));
            h = f2bf(xs[8 + e]);
            H1[e] = (short)h;  Lo1[e] = (short)f2bf(xs[8 + e] - bf2f(h));
        }
        const int sw = (arow >> 1) & 3;
        const int ra = arow * 64;
        unsigned char* a0 = s_raw + (buf * 2 + 0) * 8192 + ra;
        unsigned char* a1 = s_raw + (buf * 2 + 1) * 8192 + ra;
        const int q0 = ((2 * ahalf) ^ sw) << 4, q1 = ((2 * ahalf + 1) ^ sw) << 4;
        *(short8v*)(a0 + q0) = H0;  *(short8v*)(a0 + q1) = H1;
        *(short8v*)(a1 + q0) = Lo0; *(short8v*)(a1 + q1) = Lo1;
    };

    auto mfma_step = [&](int buf) {
        short8v a[2][4], b[2][4];
#pragma unroll
        for (int rf = 0; rf < 4; ++rf) {
            const int row = R0 + rf * 16 + r15;
            const int off = row * 64 + ((qq ^ ((row >> 1) & 3)) << 4);
            a[0][rf] = *(const short8v*)(s_raw + (buf * 2 + 0) * 8192 + off);
            a[1][rf] = *(const short8v*)(s_raw + (buf * 2 + 1) * 8192 + off);
        }
#pragma unroll
        for (int cf = 0; cf < 4; ++cf) {
            const int n = C0 + cf * 16 + r15;
            const int off = n * 64 + ((qq ^ ((n >> 1) & 3)) << 4);
            b[0][cf] = *(const short8v*)(s_raw + 32768 + (buf * 2 + 0) * 8192 + off);
            b[1][cf] = *(const short8v*)(s_raw + 32768 + (buf * 2 + 1) * 8192 + off);
        }
        // 3-term split: lo*hi + hi*lo + hi*hi (lo*lo dropped, ~2^-18 relative)
#pragma unroll
        for (int rf = 0; rf < 4; ++rf)
#pragma unroll
            for (int cf = 0; cf < 4; ++cf)
                acc[rf][cf] = __builtin_amdgcn_mfma_f32_16x16x32_bf16(
                    a[1][rf], b[0][cf], acc[rf][cf], 0, 0, 0);
#pragma unroll
        for (int rf = 0; rf < 4; ++rf)
#pragma unroll
            for (int cf = 0; cf < 4; ++cf)
                acc[rf][cf] = __builtin_amdgcn_mfma_f32_16x16x32_bf16(
                    a[0][rf], b[1][cf], acc[rf][cf], 0, 0, 0);
#pragma unroll
        for (int rf = 0; rf < 4; ++rf)
#pragma unroll
            for (int cf = 0; cf < 4; ++cf)
                acc[rf][cf] = __builtin_amdgcn_mfma_f32_16x16x32_bf16(
                    a[0][rf], b[0][cf], acc[rf][cf], 0, 0, 0);
    };

    if constexpr (APL) {
        stage(0, 0);
        __syncthreads();
#pragma unroll 2
        for (int kt = 0; kt < 16; ++kt) {
            const int cb = kt & 1;
            if (kt < 15) stage(cb ^ 1, kt + 1);   // loads in flight under MFMA
            mfma_step(cb);
            __syncthreads();
        }
    } else {
        loadA(0);
        stage(0, 0);          // B only (A skipped by constexpr)
        writeA(0);
        __syncthreads();
#pragma unroll 2
        for (int kt = 0; kt < 16; ++kt) {
            const int cb = kt & 1;
            if (kt < 15) { loadA(kt + 1); stage(cb ^ 1, kt + 1); }
            mfma_step(cb);
            if (kt < 15) writeA(cb ^ 1);
            __syncthreads();
        }
    }

    // ---- stage head-weight planes into s_hB ----
    {
        const int pl = tid >> 7, idx = tid & 127, c = idx >> 2, kq = idx & 3;
        const unsigned short* hp = headPl + ((size_t)(set * 2 + pl) * 32 + c) * 1024 + hc + kq * 32;
        short8v h0 = *(const short8v*)(hp);      short8v h1 = *(const short8v*)(hp + 8);
        short8v h2 = *(const short8v*)(hp + 16); short8v h3 = *(const short8v*)(hp + 24);
        unsigned char* d = s_raw + 33792 + pl * 8704 + c * 272 + kq * 64;
        ((short8v*)d)[0] = h0; ((short8v*)d)[1] = h1; ((short8v*)d)[2] = h2; ((short8v*)d)[3] = h3;
    }

    float* sh = (float*)s_raw;   // [64][132]
#pragma unroll 1
    for (int half = 0; half < 2; ++half) {
        if ((w >> 1) == half) {           // owning waves write bias+relu(h) rows
#pragma unroll
            for (int rf = 0; rf < 4; ++rf)
#pragma unroll
                for (int cf = 0; cf < 4; ++cf) {
                    const int c = C0 + cf * 16 + r15;
                    const float bs = s_bias[c];
#pragma unroll
                    for (int reg = 0; reg < 4; ++reg) {
                        const int r = rf * 16 + qq * 4 + reg;
                        sh[r * 132 + c] = fmaxf(acc[rf][cf][reg] + bs, 0.f);
                    }
                }
        }
        __syncthreads();

        f32x4 hacc[2];
        hacc[0] = (f32x4){0.f, 0.f, 0.f, 0.f};
        hacc[1] = (f32x4){0.f, 0.f, 0.f, 0.f};
#pragma unroll
        for (int ks = 0; ks < 4; ++ks) {
            const float* shp = sh + (w * 16 + r15) * 132 + ks * 32 + qq * 8;
            const float4 f0 = *(const float4*)(shp);
            const float4 f1 = *(const float4*)(shp + 4);
            const float xs[8] = {f0.x, f0.y, f0.z, f0.w, f1.x, f1.y, f1.z, f1.w};
            short8v ah, al;
#pragma unroll
            for (int j = 0; j < 8; ++j) {
                const unsigned short h = f2bf(xs[j]);
                ah[j] = (short)h;
                al[j] = (short)f2bf(xs[j] - bf2f(h));
            }
#pragma unroll
            for (int cf = 0; cf < 2; ++cf) {
                const unsigned char* hb = s_raw + 33792 + (cf * 16 + r15) * 272 + ks * 64 + qq * 16;
                const short8v b0 = *(const short8v*)(hb);          // hi plane
                const short8v b1v = *(const short8v*)(hb + 8704);  // lo plane
                hacc[cf] = __builtin_amdgcn_mfma_f32_16x16x32_bf16(al, b0, hacc[cf], 0, 0, 0);
                hacc[cf] = __builtin_amdgcn_mfma_f32_16x16x32_bf16(ah, b1v, hacc[cf], 0, 0, 0);
                hacc[cf] = __builtin_amdgcn_mfma_f32_16x16x32_bf16(ah, b0, hacc[cf], 0, 0, 0);
            }
        }
#pragma unroll
        for (int cf = 0; cf < 2; ++cf) {
            const int c = cf * 16 + r15;
            if (c < CT) {
#pragma unroll
                for (int reg = 0; reg < 4; ++reg) {
                    const int rl = half * 64 + w * 16 + qq * 4 + reg;
                    if (rl < nrows)
                        atomicAdd(&L[(size_t)s_idx[rl] * 20 + c], hacc[cf][reg]);
                }
            }
        }
        __syncthreads();
    }
}

// ---------------- epilogues ----------------
__global__ __launch_bounds__(256)
void k_epi_mt(const float* __restrict__ metaL, const float* __restrict__ termL,
              float* __restrict__ out, const int* __restrict__ execopt,
              const void* __restrict__ dones, const int* __restrict__ dflag,
              int* __restrict__ counts, unsigned short* __restrict__ buckets)
{
    const int g = blockIdx.x * 256 + threadIdx.x;
    const float* lr = metaL + (size_t)g * 20;
    float m = lr[0]; int am = 0;
#pragma unroll
    for (int j = 1; j < 8; ++j) { const float x = lr[j]; if (x > m) { m = x; am = j; } }
    float s = 0.f;
#pragma unroll
    for (int j = 0; j < 8; ++j) s += expf(lr[j] - m);
    out[3 * Bn + g] = (float)am;
    out[4 * Bn + g] = lr[8];
    out[5 * Bn + g] = -logf(s);

    const int eo = execopt[g];
    const float logit = termL[(size_t)g * 20 + eo];
    const float p = 1.f / (1.f + expf(-logit));
    out[6 * Bn + g] = p;
    bool dn;
    if (*dflag) dn = ((const unsigned char*)dones)[g] != 0;
    else        dn = ((const int*)dones)[g] != 0;
    const int no = (dn || (p > 0.5f)) ? am : eo;
    const int pos = atomicAdd(&counts[no], 1);
    buckets[(no << 15) + pos] = (unsigned short)g;
}

__global__ __launch_bounds__(256)
void k_epi_sub(const float* __restrict__ L, float* __restrict__ out)
{
    const int g = blockIdx.x * 256 + threadIdx.x;
    const float* lr = L + (size_t)g * 20;
    float m = lr[0]; int am = 0;
#pragma unroll
    for (int j = 1; j < 16; ++j) { const float x = lr[j]; if (x > m) { m = x; am = j; } }
    float s = 0.f;
#pragma unroll
    for (int j = 0; j < 16; ++j) s += expf(lr[j] - m);
    out[0 * Bn + g] = (float)am;
    out[1 * Bn + g] = lr[16];
    out[2 * Bn + g] = -logf(s);
}

// ================= Round-2 fp32 fallback (passing) =================
template<int CA, int CB, bool HASBIAS, int MODE>
__global__ __launch_bounds__(256, 2)
void k_fused_fb(const float* __restrict__ obs, const float* __restrict__ WhB,
                const float* __restrict__ biasB, const float* __restrict__ WAB,
                const float* __restrict__ WBB, float* __restrict__ out,
                int* __restrict__ counts, unsigned short* __restrict__ buckets,
                const void* __restrict__ dones, const int* __restrict__ dflag,
                const int* __restrict__ execopt)
{
    constexpr int CT  = CA + CB;
    constexpr int CPT = (CT + 3) / 4;

    __shared__ float s_obsT[16][68];
    __shared__ float s_W[16][132];
    __shared__ float s_h[64][132];
    __shared__ float s_WhT[17][132];
    __shared__ float s_logits[64][20];
    __shared__ float s_bias[128];
    __shared__ int   s_idx[64];

    const int tid = threadIdx.x;
    int nrows = 64;
    const float* Wh = WhB; const float* bias = biasB;
    const float* WA = WAB; const float* WB = WBB;

    if constexpr (MODE == 2) {
        const int o = blockIdx.x >> 9;
        const int t = blockIdx.x & 511;
        const int n = counts[o];
        const int start = t * 64;
        if (start >= n) return;
        nrows = min(64, n - start);
        if (tid < 64) s_idx[tid] = (int)buckets[o * Bn + start + min(tid, nrows - 1)];
        Wh = WhB + (size_t)o * Dk * Hn; bias = biasB + (size_t)o * Hn;
        WA = WAB + (size_t)o * Hn * 16; WB = WBB + (size_t)o * Hn;
    } else {
        if (tid < 64) s_idx[tid] = blockIdx.x * 64 + tid;
    }
    __syncthreads();

    const int tc = tid & 15, tr = tid >> 4;
    const int hr = tid >> 2, hq = tid & 3;
    const int ld_row = tid >> 2, ld_kk = (tid & 3) * 4;

    float head_acc[CPT];
#pragma unroll
    for (int i = 0; i < CPT; ++i) head_acc[i] = 0.f;

    for (int hcc = 0; hcc < Hn; hcc += 128) {
        for (int e = tid; e < CT * 128; e += 256) {
            const int c = e >> 7, j = e & 127;
            float v;
            if (c < CA) v = WA[(size_t)(hcc + j) * CA + c];
            else        v = WB[(size_t)(hcc + j) * CB + (c - CA)];
            s_WhT[c][j] = v;
        }
        if constexpr (HASBIAS) { if (tid < 128) s_bias[tid] = bias[hcc + tid]; }

        float acc[4][8];
#pragma unroll
        for (int i = 0; i < 4; ++i)
#pragma unroll
            for (int j = 0; j < 8; ++j) acc[i][j] = 0.f;

        for (int kt = 0; kt < Dk; kt += 16) {
            __syncthreads();
            {
                const int gr = s_idx[ld_row];
                const float4 v = *reinterpret_cast<const float4*>(obs + (size_t)gr * Dk + kt + ld_kk);
                s_obsT[ld_kk + 0][ld_row] = v.x; s_obsT[ld_kk + 1][ld_row] = v.y;
                s_obsT[ld_kk + 2][ld_row] = v.z; s_obsT[ld_kk + 3][ld_row] = v.w;
            }
#pragma unroll
            for (int p = 0; p < 2; ++p) {
                const int Li = tid + p * 256;
                const int k = Li >> 5, cg = (Li & 31) * 4;
                *reinterpret_cast<float4*>(&s_W[k][cg]) =
                    *reinterpret_cast<const float4*>(Wh + (size_t)(kt + k) * Hn + hcc + cg);
            }
            __syncthreads();
#pragma unroll
            for (int k = 0; k < 16; ++k) {
                const float4 avv = *reinterpret_cast<const float4*>(&s_obsT[k][tr * 4]);
                const float4 b0 = *reinterpret_cast<const float4*>(&s_W[k][tc * 4]);
                const float4 b1 = *reinterpret_cast<const float4*>(&s_W[k][64 + tc * 4]);
                float a_[4] = {avv.x, avv.y, avv.z, avv.w};
                float b_[8] = {b0.x, b0.y, b0.z, b0.w, b1.x, b1.y, b1.z, b1.w};
#pragma unroll
                for (int i = 0; i < 4; ++i)
#pragma unroll
                    for (int j = 0; j < 8; ++j) acc[i][j] = fmaf(a_[i], b_[j], acc[i][j]);
            }
        }

#pragma unroll
        for (int i = 0; i < 4; ++i) {
            const int r = tr * 4 + i;
            float4 v0, v1;
            v0.x = acc[i][0]; v0.y = acc[i][1]; v0.z = acc[i][2]; v0.w = acc[i][3];
            v1.x = acc[i][4]; v1.y = acc[i][5]; v1.z = acc[i][6]; v1.w = acc[i][7];
            if constexpr (HASBIAS) {
                v0.x += s_bias[tc * 4 + 0]; v0.y += s_bias[tc * 4 + 1];
                v0.z += s_bias[tc * 4 + 2]; v0.w += s_bias[tc * 4 + 3];
                v1.x += s_bias[64 + tc * 4 + 0]; v1.y += s_bias[64 + tc * 4 + 1];
                v1.z += s_bias[64 + tc * 4 + 2]; v1.w += s_bias[64 + tc * 4 + 3];
            }
            v0.x = fmaxf(v0.x, 0.f); v0.y = fmaxf(v0.y, 0.f);
            v0.z = fmaxf(v0.z, 0.f); v0.w = fmaxf(v0.w, 0.f);
            v1.x = fmaxf(v1.x, 0.f); v1.y = fmaxf(v1.y, 0.f);
            v1.z = fmaxf(v1.z, 0.f); v1.w = fmaxf(v1.w, 0.f);
            *reinterpret_cast<float4*>(&s_h[r][tc * 4]) = v0;
            *reinterpret_cast<float4*>(&s_h[r][64 + tc * 4]) = v1;
        }
        __syncthreads();
        {
            const float* hrow = s_h[hr];
#pragma unroll
            for (int i = 0; i < CPT; ++i) {
                const int c = hq * CPT + i;
                if (c < CT) {
                    const float* wrow = s_WhT[c];
                    float a = head_acc[i];
#pragma unroll
                    for (int j = 0; j < 128; j += 4) {
                        const float4 hv = *reinterpret_cast<const float4*>(&hrow[j]);
                        const float4 wv = *reinterpret_cast<const float4*>(&wrow[j]);
                        a = fmaf(hv.x, wv.x, a); a = fmaf(hv.y, wv.y, a);
                        a = fmaf(hv.z, wv.z, a); a = fmaf(hv.w, wv.w, a);
                    }
                    head_acc[i] = a;
                }
            }
        }
        __syncthreads();
    }

#pragma unroll
    for (int i = 0; i < CPT; ++i) {
        const int c = hq * CPT + i;
        if (c < CT) s_logits[hr][c] = head_acc[i];
    }
    __syncthreads();

    if constexpr (MODE == 0) {
        if (tid < 64) {
            const int g = s_idx[tid];
            float m = s_logits[tid][0]; int am = 0;
#pragma unroll
            for (int j = 1; j < 8; ++j) { const float x = s_logits[tid][j]; if (x > m) { m = x; am = j; } }
            float s = 0.f;
#pragma unroll
            for (int j = 0; j < 8; ++j) s += expf(s_logits[tid][j] - m);
            out[3 * Bn + g] = (float)am;
            out[4 * Bn + g] = s_logits[tid][8];
            out[5 * Bn + g] = -logf(s);
        }
    } else if constexpr (MODE == 1) {
        if (tid < 64) {
            const int g = s_idx[tid];
            const int eo = execopt[g];
            const float p = 1.f / (1.f + expf(-s_logits[tid][eo]));
            out[6 * Bn + g] = p;
            bool dn;
            if (*dflag) dn = ((const unsigned char*)dones)[g] != 0;
            else        dn = ((const int*)dones)[g] != 0;
            const int no = (dn || (p > 0.5f)) ? (int)out[3 * Bn + g] : eo;
            const int pos = atomicAdd(&counts[no], 1);
            buckets[no * Bn + pos] = (unsigned short)g;
        }
    } else {
        if (tid < nrows) {
            const int g = s_idx[tid];
            float m = s_logits[tid][0]; int am = 0;
#pragma unroll
            for (int j = 1; j < 16; ++j) { const float x = s_logits[tid][j]; if (x > m) { m = x; am = j; } }
            float s = 0.f;
#pragma unroll
            for (int j = 0; j < 16; ++j) s += expf(s_logits[tid][j] - m);
            out[0 * Bn + g] = (float)am;
            out[1 * Bn + g] = s_logits[tid][16];
            out[2 * Bn + g] = -logf(s);
        }
    }
}

// ---------------- launcher ----------------
extern "C" void kernel_launch(void* const* d_in, const int* in_sizes, int n_in,
                              void* d_out, int out_size, void* d_ws, size_t ws_size,
                              hipStream_t stream)
{
    const float* obs     = (const float*)d_in[0];
    const void*  dones   = d_in[1];
    const int*   execopt = (const int*)d_in[2];
    const float* Wm1   = (const float*)d_in[3];
    const float* bm1   = (const float*)d_in[4];
    const float* Wm_pi = (const float*)d_in[5];
    const float* Wm_v  = (const float*)d_in[6];
    const float* Wt1   = (const float*)d_in[7];
    const float* Wt2   = (const float*)d_in[8];
    const float* W1    = (const float*)d_in[9];
    const float* b1    = (const float*)d_in[10];
    const float* Wpi   = (const float*)d_in[11];
    const float* Wv    = (const float*)d_in[12];
    float* out = (float*)d_out;

    unsigned char* ws = (unsigned char*)d_ws;
    int* counts = (int*)(ws + WS_COUNTS);
    int* dflag  = (int*)(ws + WS_DFLAG);
    unsigned short* buckets = (unsigned short*)(ws + WS_BUCKETS);

    hipMemsetAsync(d_ws, 0, 64, stream);
    k_detect<<<1, 256, 0, stream>>>((const unsigned int*)dones, dflag);

    if (ws_size >= MID_NEED) {
        float* metaL = (float*)(ws + WS_LOGITS);
        float* termL = (float*)(ws + WS_LOGITS + LOG_SZ);
        float* subL  = (float*)(ws + WS_LOGITS + 2 * LOG_SZ);
        unsigned short* hidPl  = (unsigned short*)(ws + WS_HID);
        unsigned short* headPl = (unsigned short*)(ws + WS_HEAD);
        unsigned short* obsPl  = (unsigned short*)(ws + WS_OBS);

        hipMemsetAsync(ws + WS_LOGITS, 0, 3 * LOG_SZ, stream);
        k_split_hid<<<1280, 256, 0, stream>>>(Wm1, Wt1, W1, hidPl);
        k_split_head<<<320, 256, 0, stream>>>(Wm_pi, Wm_v, Wt2, Wpi, Wv, headPl);

        if (ws_size >= FULL_NEED) {
            k_split_obs<<<8192, 256, 0, stream>>>(obs, obsPl);
            k_gemm<3, true><<<4096, 256, 0, stream>>>(
                obs, obsPl, hidPl, headPl, bm1, b1, metaL, termL, subL, counts, buckets);
            k_epi_mt<<<128, 256, 0, stream>>>(metaL, termL, out, execopt, dones, dflag, counts, buckets);
            k_gemm<2, true><<<16384, 256, 0, stream>>>(
                obs, obsPl, hidPl, headPl, bm1, b1, metaL, termL, subL, counts, buckets);
            k_epi_sub<<<128, 256, 0, stream>>>(subL, out);
        } else {
            k_gemm<3, false><<<4096, 256, 0, stream>>>(
                obs, nullptr, hidPl, headPl, bm1, b1, metaL, termL, subL, counts, buckets);
            k_epi_mt<<<128, 256, 0, stream>>>(metaL, termL, out, execopt, dones, dflag, counts, buckets);
            k_gemm<2, false><<<16384, 256, 0, stream>>>(
                obs, nullptr, hidPl, headPl, bm1, b1, metaL, termL, subL, counts, buckets);
            k_epi_sub<<<128, 256, 0, stream>>>(subL, out);
        }
    } else {
        k_fused_fb<8, 1, true, 0><<<Bn / 64, 256, 0, stream>>>(
            obs, Wm1, bm1, Wm_pi, Wm_v, out, counts, buckets, dones, dflag, execopt);
        k_fused_fb<8, 0, false, 1><<<Bn / 64, 256, 0, stream>>>(
            obs, Wt1, nullptr, Wt2, nullptr, out, counts, buckets, dones, dflag, execopt);
        k_fused_fb<16, 1, true, 2><<<8 * (Bn / 64), 256, 0, stream>>>(
            obs, W1, b1, Wpi, Wv, out, counts, buckets, dones, dflag, execopt);
    }
}